// Round 1
// baseline (1451.561 us; speedup 1.0000x reference)
//
#include <hip/hip_runtime.h>

typedef _Float16 half8 __attribute__((ext_vector_type(8)));
typedef float floatx4 __attribute__((ext_vector_type(4)));

#define CIN 32
#define COUT 32
#define KOFF 27
#define EPSV 1e-5f

// ---------------------------------------------------------------------------
// ws layout:
//   [0, N*32*2)          feats16 (f16 copy of feats)        64 MB
//   [+, +55296)          Wpack: B-fragments, f16            55 KB
//   [align 512, +768)    stats: sum[32], sumsq[32], scale[32], shift[32], flag
// y (pre-BN conv output, fp32) lives in d_out and is normalized in place.
// ---------------------------------------------------------------------------

__global__ void cvt_feats(const float* __restrict__ feats,
                          _Float16* __restrict__ f16, int total8) {
  int t = blockIdx.x * blockDim.x + threadIdx.x;
  if (t >= total8) return;
  const floatx4* in4 = (const floatx4*)feats;
  floatx4 a = in4[t * 2];
  floatx4 b = in4[t * 2 + 1];
  half8 h;
  h[0] = (_Float16)a[0]; h[1] = (_Float16)a[1];
  h[2] = (_Float16)a[2]; h[3] = (_Float16)a[3];
  h[4] = (_Float16)b[0]; h[5] = (_Float16)b[1];
  h[6] = (_Float16)b[2]; h[7] = (_Float16)b[3];
  *(half8*)(f16 + (size_t)t * 8) = h;
}

// Wpack[ko][h][lane][j] = W[ko][k = (lane>>4)*8 + j][co = h*16 + (lane&15)]
// This is exactly the B-operand fragment for mfma_f32_16x16x32_f16.
__global__ void pack_w(const float* __restrict__ W, _Float16* __restrict__ wp) {
  int ko = blockIdx.x;
  int h = threadIdx.x >> 6;
  int lane = threadIdx.x & 63;
  int col = lane & 15, quad = lane >> 4;
  half8 p;
#pragma unroll
  for (int j = 0; j < 8; ++j) {
    int k = quad * 8 + j;
    p[j] = (_Float16)W[(ko * CIN + k) * COUT + h * 16 + col];
  }
  *(half8*)(wp + ((size_t)(ko * 2 + h) * 64 + lane) * 8) = p;
}

// If mask arrived as int32 (little-endian 0/1), all bytes at offset%4!=0 are 0.
// If it's 1-byte bool (bernoulli 0.5), ~half of those bytes are nonzero.
__global__ void detect_mask(const unsigned char* __restrict__ m,
                            int* __restrict__ flag) {
  int tid = threadIdx.x;
  int any = 0;
  for (int i = tid; i < 4096; i += 256) {
    if ((i & 3) != 0 && m[i] != 0) any = 1;
  }
  if (any) atomicOr(flag, 1);
}

__launch_bounds__(256)
__global__ void conv_mfma(const _Float16* __restrict__ f16,
                          const _Float16* __restrict__ wp,
                          const int* __restrict__ nidx,
                          const unsigned char* __restrict__ nmask,
                          const int* __restrict__ flagp,
                          float* __restrict__ y, int N) {
  int wave = threadIdx.x >> 6;
  int lane = threadIdx.x & 63;
  int base = (blockIdx.x * 4 + wave) * 64;  // 64 voxels per wave
  if (base >= N) return;
  int col = lane & 15, quad = lane >> 4;
  bool bytemode = (*flagp != 0);
  const int* nmask32 = (const int*)nmask;
  const half8* wfrag = (const half8*)wp;

  floatx4 acc[4][2];
#pragma unroll
  for (int t = 0; t < 4; ++t)
#pragma unroll
    for (int h = 0; h < 2; ++h) {
      acc[t][h][0] = 0.f; acc[t][h][1] = 0.f;
      acc[t][h][2] = 0.f; acc[t][h][3] = 0.f;
    }

#pragma unroll 1
  for (int ko = 0; ko < KOFF; ++ko) {
    half8 b0 = wfrag[(size_t)(ko * 2 + 0) * 64 + lane];
    half8 b1 = wfrag[(size_t)(ko * 2 + 1) * 64 + lane];
#pragma unroll
    for (int t = 0; t < 4; ++t) {
      int vox = base + t * 16 + col;        // A row m = lane&15
      int moff = vox * KOFF + ko;
      int nb = nidx[moff];
      int mk;
      if (bytemode) mk = nmask[moff];
      else          mk = nmask32[moff];
      half8 a;
#pragma unroll
      for (int j = 0; j < 8; ++j) a[j] = (_Float16)0.f;
      if (mk != 0) {
        // A[m][k]: k = quad*8 + j  -> 16B chunk of the gathered f16 row
        a = *(const half8*)(f16 + (size_t)nb * CIN + quad * 8);
      }
      acc[t][0] = __builtin_amdgcn_mfma_f32_16x16x32_f16(a, b0, acc[t][0], 0, 0, 0);
      acc[t][1] = __builtin_amdgcn_mfma_f32_16x16x32_f16(a, b1, acc[t][1], 0, 0, 0);
    }
  }

  // C/D layout: n = lane&15 (co within half), m = quad*4 + r (voxel in tile)
#pragma unroll
  for (int t = 0; t < 4; ++t)
#pragma unroll
    for (int h = 0; h < 2; ++h) {
      floatx4 c = acc[t][h];
      int co = h * 16 + col;
#pragma unroll
      for (int r = 0; r < 4; ++r) {
        int vox = base + t * 16 + quad * 4 + r;
        y[(size_t)vox * COUT + co] = c[r];
      }
    }
}

__global__ void bn_stats(const float* __restrict__ y, float* __restrict__ stats,
                         int N) {
  int tid = threadIdx.x;
  int co = tid & 31, ro = tid >> 5;  // 8 rows per block-iter
  float s = 0.f, s2 = 0.f;
  for (int i = blockIdx.x * 8 + ro; i < N; i += gridDim.x * 8) {
    float v = y[(size_t)i * COUT + co];
    s += v;
    s2 += v * v;
  }
  __shared__ float sm[256];
  __shared__ float sq[256];
  sm[tid] = s;
  sq[tid] = s2;
  __syncthreads();
  for (int off = 128; off >= 32; off >>= 1) {
    if (tid < off) {
      sm[tid] += sm[tid + off];
      sq[tid] += sq[tid + off];
    }
    __syncthreads();
  }
  if (tid < 32) {
    atomicAdd(&stats[tid], sm[tid]);
    atomicAdd(&stats[32 + tid], sq[tid]);
  }
}

__global__ void bn_finalize(const float* __restrict__ gamma,
                            const float* __restrict__ beta,
                            float* __restrict__ stats, float invN) {
  int tid = threadIdx.x;
  if (tid < 32) {
    float mean = stats[tid] * invN;
    float ex2 = stats[32 + tid] * invN;
    float var = ex2 - mean * mean;
    float inv = rsqrtf(var + EPSV);
    float sc = gamma[tid] * inv;
    stats[64 + tid] = sc;
    stats[96 + tid] = beta[tid] - mean * sc;
  }
}

__global__ void bn_apply(float* __restrict__ y, const float* __restrict__ stats,
                         int total4) {
  int t = blockIdx.x * blockDim.x + threadIdx.x;
  if (t >= total4) return;
  size_t g = (size_t)t * 4;
  int co = (int)(g & 31);
  floatx4 v = *(const floatx4*)(y + g);
  floatx4 sc = *(const floatx4*)(stats + 64 + co);
  floatx4 sh = *(const floatx4*)(stats + 96 + co);
  floatx4 o;
#pragma unroll
  for (int j = 0; j < 4; ++j) o[j] = fmaxf(0.f, v[j] * sc[j] + sh[j]);
  *(floatx4*)(y + g) = o;
}

extern "C" void kernel_launch(void* const* d_in, const int* in_sizes, int n_in,
                              void* d_out, int out_size, void* d_ws,
                              size_t ws_size, hipStream_t stream) {
  const float* feats = (const float*)d_in[0];
  const float* W = (const float*)d_in[1];
  const float* gamma = (const float*)d_in[2];
  const float* beta = (const float*)d_in[3];
  const int* nidx = (const int*)d_in[4];
  const unsigned char* nmask = (const unsigned char*)d_in[5];
  float* out = (float*)d_out;

  int N = in_sizes[0] / CIN;  // 1,000,000

  char* ws = (char*)d_ws;
  size_t f16_bytes = (size_t)N * CIN * sizeof(_Float16);
  _Float16* f16 = (_Float16*)ws;
  _Float16* wp = (_Float16*)(ws + f16_bytes);
  size_t wp_bytes = (size_t)KOFF * 2 * 64 * 8 * sizeof(_Float16);
  size_t stats_off = ((f16_bytes + wp_bytes + 511) / 512) * 512;
  float* stats = (float*)(ws + stats_off);
  int* flag = (int*)(stats + 128);

  // zero sums/sumsq + flag (scale/shift written by bn_finalize)
  hipMemsetAsync(stats, 0, 132 * sizeof(float), stream);

  int total8 = N * CIN / 8;
  cvt_feats<<<(total8 + 255) / 256, 256, 0, stream>>>(feats, f16, total8);
  pack_w<<<KOFF, 128, 0, stream>>>(W, wp);
  detect_mask<<<1, 256, 0, stream>>>(nmask, flag);

  int nwaves = N / 64;  // N divisible by 64 for this problem
  conv_mfma<<<(nwaves + 3) / 4, 256, 0, stream>>>(f16, wp, nidx, nmask, flag,
                                                  out, N);

  bn_stats<<<1024, 256, 0, stream>>>(out, stats, N);
  bn_finalize<<<1, 64, 0, stream>>>(gamma, beta, stats, 1.0f / (float)N);

  int total4 = N * COUT / 4;
  bn_apply<<<(total4 + 255) / 256, 256, 0, stream>>>(out, stats, total4);
}

// Round 2
// 745.735 us; speedup vs baseline: 1.9465x; 1.9465x over previous
//
#include <hip/hip_runtime.h>

typedef _Float16 half8 __attribute__((ext_vector_type(8)));
typedef float floatx4 __attribute__((ext_vector_type(4)));

#define CIN 32
#define COUT 32
#define KOFF 27
#define EPSV 1e-5f

// ---------------------------------------------------------------------------
// ws layout:
//   [0, N*32*2)            feats16 (f16 copy of feats)      64 MB
//   [+, +55296)            Wpack: B-fragments, f16          55 KB
//   [align 512, +768)      stats: sum/sumsq/scale/shift/flag
//   [align 256, +N*27*4)   nbrT: transposed idx|mask<<31    108 MB (if ws fits)
// y (pre-BN conv output, fp32) lives in d_out, normalized in place.
// ---------------------------------------------------------------------------

__global__ void cvt_feats(const float* __restrict__ feats,
                          _Float16* __restrict__ f16, int total8) {
  int t = blockIdx.x * blockDim.x + threadIdx.x;
  if (t >= total8) return;
  const floatx4* in4 = (const floatx4*)feats;
  floatx4 a = __builtin_nontemporal_load(&in4[t * 2]);
  floatx4 b = __builtin_nontemporal_load(&in4[t * 2 + 1]);
  half8 h;
  h[0] = (_Float16)a[0]; h[1] = (_Float16)a[1];
  h[2] = (_Float16)a[2]; h[3] = (_Float16)a[3];
  h[4] = (_Float16)b[0]; h[5] = (_Float16)b[1];
  h[6] = (_Float16)b[2]; h[7] = (_Float16)b[3];
  *(half8*)(f16 + (size_t)t * 8) = h;   // temporal: want it cache-resident
}

// Wpack[ko][h][lane][j] = W[ko][k=(lane>>4)*8+j][co=h*16+(lane&15)]
__global__ void pack_w(const float* __restrict__ W, _Float16* __restrict__ wp) {
  int ko = blockIdx.x;
  int h = threadIdx.x >> 6;
  int lane = threadIdx.x & 63;
  int col = lane & 15, quad = lane >> 4;
  half8 p;
#pragma unroll
  for (int j = 0; j < 8; ++j) {
    int k = quad * 8 + j;
    p[j] = (_Float16)W[(ko * CIN + k) * COUT + h * 16 + col];
  }
  *(half8*)(wp + ((size_t)(ko * 2 + h) * 64 + lane) * 8) = p;
}

// int32 mask => bytes at offset%4!=0 are all zero; byte mask => ~50% nonzero.
__global__ void detect_mask(const unsigned char* __restrict__ m,
                            int* __restrict__ flag) {
  int tid = threadIdx.x;
  int any = 0;
  for (int i = tid; i < 4096; i += 256) {
    if ((i & 3) != 0 && m[i] != 0) any = 1;
  }
  if (any) atomicOr(flag, 1);
}

// Transpose neighbor map: nbrT[ko*N + vox] = idx | (valid ? 1<<31 : 0).
// Coalesced read of [256 vox x 27] tile -> LDS -> coalesced per-ko writes.
__global__ void pack_nbr(const int* __restrict__ nidx,
                         const unsigned char* __restrict__ nmask,
                         const int* __restrict__ flagp,
                         int* __restrict__ nbrT, int N) {
  __shared__ int lds[256 * 28];
  bool bytemode = (*flagp != 0);
  const int* nmask32 = (const int*)nmask;
  int tileBase = blockIdx.x * 256;
  int tid = threadIdx.x;
  int nvox = min(256, N - tileBase);
  int total = nvox * KOFF;
  for (int p = tid; p < total; p += 256) {
    int voxl = p / KOFF;
    int ko = p - voxl * KOFF;
    int g = tileBase * KOFF + p;
    int idx = __builtin_nontemporal_load(&nidx[g]);
    int mk = bytemode ? (int)__builtin_nontemporal_load(&nmask[g])
                      : __builtin_nontemporal_load(&nmask32[g]);
    lds[voxl * 28 + ko] = (idx & 0x7FFFFFFF) | (mk ? (int)0x80000000 : 0);
  }
  __syncthreads();
  for (int ko = 0; ko < KOFF; ++ko) {
    if (tid < nvox)
      nbrT[(size_t)ko * N + tileBase + tid] = lds[tid * 28 + ko];
  }
}

__launch_bounds__(256)
__global__ void conv_mfma_t(const _Float16* __restrict__ f16,
                            const _Float16* __restrict__ wp,
                            const int* __restrict__ nbrT,
                            float* __restrict__ y, int N) {
  int wave = threadIdx.x >> 6;
  int lane = threadIdx.x & 63;
  int base = (blockIdx.x * 4 + wave) * 64;
  if (base >= N) return;
  int col = lane & 15, quad = lane >> 4;
  const half8* wfrag = (const half8*)wp;

  floatx4 acc[4][2];
#pragma unroll
  for (int t = 0; t < 4; ++t)
#pragma unroll
    for (int h = 0; h < 2; ++h) {
      acc[t][h][0] = 0.f; acc[t][h][1] = 0.f;
      acc[t][h][2] = 0.f; acc[t][h][3] = 0.f;
    }

#pragma unroll 3
  for (int ko = 0; ko < KOFF; ++ko) {
    half8 b0 = wfrag[(size_t)(ko * 2 + 0) * 64 + lane];
    half8 b1 = wfrag[(size_t)(ko * 2 + 1) * 64 + lane];
    const int* row = nbrT + (size_t)ko * N + base;
#pragma unroll
    for (int t = 0; t < 4; ++t) {
      int v = __builtin_nontemporal_load(&row[t * 16 + col]);
      half8 a;
#pragma unroll
      for (int j = 0; j < 8; ++j) a[j] = (_Float16)0.f;
      if (v < 0) {  // bit31 == valid
        int nb = v & 0x7FFFFFFF;
        a = *(const half8*)(f16 + (size_t)nb * CIN + quad * 8);
      }
      acc[t][0] = __builtin_amdgcn_mfma_f32_16x16x32_f16(a, b0, acc[t][0], 0, 0, 0);
      acc[t][1] = __builtin_amdgcn_mfma_f32_16x16x32_f16(a, b1, acc[t][1], 0, 0, 0);
    }
  }

#pragma unroll
  for (int t = 0; t < 4; ++t)
#pragma unroll
    for (int h = 0; h < 2; ++h) {
      floatx4 c = acc[t][h];
      int co = h * 16 + col;
#pragma unroll
      for (int r = 0; r < 4; ++r) {
        int vox = base + t * 16 + quad * 4 + r;
        y[(size_t)vox * COUT + co] = c[r];
      }
    }
}

// Fallback (round-1 structure) if ws can't fit nbrT.
__launch_bounds__(256)
__global__ void conv_mfma_d(const _Float16* __restrict__ f16,
                            const _Float16* __restrict__ wp,
                            const int* __restrict__ nidx,
                            const unsigned char* __restrict__ nmask,
                            const int* __restrict__ flagp,
                            float* __restrict__ y, int N) {
  int wave = threadIdx.x >> 6;
  int lane = threadIdx.x & 63;
  int base = (blockIdx.x * 4 + wave) * 64;
  if (base >= N) return;
  int col = lane & 15, quad = lane >> 4;
  bool bytemode = (*flagp != 0);
  const int* nmask32 = (const int*)nmask;
  const half8* wfrag = (const half8*)wp;

  floatx4 acc[4][2];
#pragma unroll
  for (int t = 0; t < 4; ++t)
#pragma unroll
    for (int h = 0; h < 2; ++h) {
      acc[t][h][0] = 0.f; acc[t][h][1] = 0.f;
      acc[t][h][2] = 0.f; acc[t][h][3] = 0.f;
    }

#pragma unroll 1
  for (int ko = 0; ko < KOFF; ++ko) {
    half8 b0 = wfrag[(size_t)(ko * 2 + 0) * 64 + lane];
    half8 b1 = wfrag[(size_t)(ko * 2 + 1) * 64 + lane];
#pragma unroll
    for (int t = 0; t < 4; ++t) {
      int vox = base + t * 16 + col;
      int moff = vox * KOFF + ko;
      int nb = nidx[moff];
      int mk = bytemode ? (int)nmask[moff] : nmask32[moff];
      half8 a;
#pragma unroll
      for (int j = 0; j < 8; ++j) a[j] = (_Float16)0.f;
      if (mk != 0) {
        a = *(const half8*)(f16 + (size_t)nb * CIN + quad * 8);
      }
      acc[t][0] = __builtin_amdgcn_mfma_f32_16x16x32_f16(a, b0, acc[t][0], 0, 0, 0);
      acc[t][1] = __builtin_amdgcn_mfma_f32_16x16x32_f16(a, b1, acc[t][1], 0, 0, 0);
    }
  }

#pragma unroll
  for (int t = 0; t < 4; ++t)
#pragma unroll
    for (int h = 0; h < 2; ++h) {
      floatx4 c = acc[t][h];
      int co = h * 16 + col;
#pragma unroll
      for (int r = 0; r < 4; ++r) {
        int vox = base + t * 16 + quad * 4 + r;
        y[(size_t)vox * COUT + co] = c[r];
      }
    }
}

__global__ void bn_stats(const float* __restrict__ y, float* __restrict__ stats,
                         int N) {
  int tid = threadIdx.x;
  int co = tid & 31, ro = tid >> 5;
  float s = 0.f, s2 = 0.f;
  for (int i = blockIdx.x * 8 + ro; i < N; i += gridDim.x * 8) {
    float v = y[(size_t)i * COUT + co];
    s += v;
    s2 += v * v;
  }
  __shared__ float sm[256];
  __shared__ float sq[256];
  sm[tid] = s;
  sq[tid] = s2;
  __syncthreads();
  for (int off = 128; off >= 32; off >>= 1) {
    if (tid < off) {
      sm[tid] += sm[tid + off];
      sq[tid] += sq[tid + off];
    }
    __syncthreads();
  }
  if (tid < 32) {
    atomicAdd(&stats[tid], sm[tid]);
    atomicAdd(&stats[32 + tid], sq[tid]);
  }
}

__global__ void bn_finalize(const float* __restrict__ gamma,
                            const float* __restrict__ beta,
                            float* __restrict__ stats, float invN) {
  int tid = threadIdx.x;
  if (tid < 32) {
    float mean = stats[tid] * invN;
    float ex2 = stats[32 + tid] * invN;
    float var = ex2 - mean * mean;
    float inv = rsqrtf(var + EPSV);
    float sc = gamma[tid] * inv;
    stats[64 + tid] = sc;
    stats[96 + tid] = beta[tid] - mean * sc;
  }
}

__global__ void bn_apply(float* __restrict__ y, const float* __restrict__ stats,
                         int total4) {
  int t = blockIdx.x * blockDim.x + threadIdx.x;
  if (t >= total4) return;
  size_t g = (size_t)t * 4;
  int co = (int)(g & 31);
  floatx4 v = *(const floatx4*)(y + g);
  floatx4 sc = *(const floatx4*)(stats + 64 + co);
  floatx4 sh = *(const floatx4*)(stats + 96 + co);
  floatx4 o;
#pragma unroll
  for (int j = 0; j < 4; ++j) o[j] = fmaxf(0.f, v[j] * sc[j] + sh[j]);
  *(floatx4*)(y + g) = o;
}

extern "C" void kernel_launch(void* const* d_in, const int* in_sizes, int n_in,
                              void* d_out, int out_size, void* d_ws,
                              size_t ws_size, hipStream_t stream) {
  const float* feats = (const float*)d_in[0];
  const float* W = (const float*)d_in[1];
  const float* gamma = (const float*)d_in[2];
  const float* beta = (const float*)d_in[3];
  const int* nidx = (const int*)d_in[4];
  const unsigned char* nmask = (const unsigned char*)d_in[5];
  float* out = (float*)d_out;

  int N = in_sizes[0] / CIN;  // 1,000,000

  char* ws = (char*)d_ws;
  size_t f16_bytes = (size_t)N * CIN * sizeof(_Float16);
  _Float16* f16 = (_Float16*)ws;
  _Float16* wp = (_Float16*)(ws + f16_bytes);
  size_t wp_bytes = (size_t)KOFF * 2 * 64 * 8 * sizeof(_Float16);
  size_t stats_off = ((f16_bytes + wp_bytes + 511) / 512) * 512;
  float* stats = (float*)(ws + stats_off);
  int* flag = (int*)(stats + 128);
  size_t nbrT_off = ((stats_off + 768 + 255) / 256) * 256;
  size_t nbrT_bytes = (size_t)N * KOFF * sizeof(int);
  int* nbrT = (int*)(ws + nbrT_off);
  bool use_transpose = (nbrT_off + nbrT_bytes) <= ws_size;

  hipMemsetAsync(stats, 0, 132 * sizeof(float), stream);

  int total8 = N * CIN / 8;
  cvt_feats<<<(total8 + 255) / 256, 256, 0, stream>>>(feats, f16, total8);
  pack_w<<<KOFF, 128, 0, stream>>>(W, wp);
  detect_mask<<<1, 256, 0, stream>>>(nmask, flag);

  int nwaves = N / 64;
  int nblocks = (nwaves + 3) / 4;
  if (use_transpose) {
    pack_nbr<<<(N + 255) / 256, 256, 0, stream>>>(nidx, nmask, flag, nbrT, N);
    conv_mfma_t<<<nblocks, 256, 0, stream>>>(f16, wp, nbrT, out, N);
  } else {
    conv_mfma_d<<<nblocks, 256, 0, stream>>>(f16, wp, nidx, nmask, flag, out, N);
  }

  bn_stats<<<1024, 256, 0, stream>>>(out, stats, N);
  bn_finalize<<<1, 64, 0, stream>>>(gamma, beta, stats, 1.0f / (float)N);

  int total4 = N * COUT / 4;
  bn_apply<<<(total4 + 255) / 256, 256, 0, stream>>>(out, stats, total4);
}

// Round 3
// 736.094 us; speedup vs baseline: 1.9720x; 1.0131x over previous
//
#include <hip/hip_runtime.h>

typedef _Float16 half8 __attribute__((ext_vector_type(8)));
typedef float floatx4 __attribute__((ext_vector_type(4)));

#define CIN 32
#define COUT 32
#define KOFF 27
#define EPSV 1e-5f

// ---------------------------------------------------------------------------
// ws layout:
//   [0, N*32*2)            feats16 (f16 copy of feats)      64 MB
//   [+, +55296)            Wpack: B-fragments, f16          55 KB
//   [align 512, +768)      stats: sum[32], sumsq[32], flag
//   [align 256, +N*27*4)   nbrT: transposed idx|mask<<31    108 MB
// y (pre-BN conv output, fp32) lives in d_out, normalized in place.
// Dispatches: memset, setup(pack_w+detect), prep(cvt+pack_nbr),
//             conv(+fused BN stats), bn_apply(+inline finalize).
// ---------------------------------------------------------------------------

// blocks 0..26: pack W fragments; block 27: detect mask dtype.
__global__ void setup_k(const float* __restrict__ W, _Float16* __restrict__ wp,
                        const unsigned char* __restrict__ m,
                        int* __restrict__ flag) {
  if (blockIdx.x < KOFF) {
    int ko = blockIdx.x;
    int h = threadIdx.x >> 6;        // 128 threads: 2 halves
    int lane = threadIdx.x & 63;
    int col = lane & 15, quad = lane >> 4;
    half8 p;
#pragma unroll
    for (int j = 0; j < 8; ++j) {
      int k = quad * 8 + j;
      p[j] = (_Float16)W[(ko * CIN + k) * COUT + h * 16 + col];
    }
    *(half8*)(wp + ((size_t)(ko * 2 + h) * 64 + lane) * 8) = p;
  } else {
    // int32 mask => bytes at offset%4!=0 all zero; byte mask => ~50% nonzero
    int tid = threadIdx.x;
    int any = 0;
    for (int i = tid; i < 4096; i += 128) {
      if ((i & 3) != 0 && m[i] != 0) any = 1;
    }
    if (any) atomicOr(flag, 1);
  }
}

// blocks [0,cvtBlocks): feats fp32->f16.  rest: transpose neighbor map.
__global__ void prep_k(const float* __restrict__ feats,
                       _Float16* __restrict__ f16, int total8,
                       const int* __restrict__ nidx,
                       const unsigned char* __restrict__ nmask,
                       const int* __restrict__ flagp,
                       int* __restrict__ nbrT, int N, int cvtBlocks) {
  __shared__ int lds[256 * 29];
  int tid = threadIdx.x;
  if ((int)blockIdx.x < cvtBlocks) {
    int t = blockIdx.x * 256 + tid;
    if (t >= total8) return;
    const floatx4* in4 = (const floatx4*)feats;
    floatx4 a = __builtin_nontemporal_load(&in4[t * 2]);
    floatx4 b = __builtin_nontemporal_load(&in4[t * 2 + 1]);
    half8 h;
    h[0] = (_Float16)a[0]; h[1] = (_Float16)a[1];
    h[2] = (_Float16)a[2]; h[3] = (_Float16)a[3];
    h[4] = (_Float16)b[0]; h[5] = (_Float16)b[1];
    h[6] = (_Float16)b[2]; h[7] = (_Float16)b[3];
    *(half8*)(f16 + (size_t)t * 8) = h;  // temporal: keep cache-resident
  } else {
    bool bytemode = (*flagp != 0);
    const int* nmask32 = (const int*)nmask;
    int tileBase = (blockIdx.x - cvtBlocks) * 256;
    int nvox = min(256, N - tileBase);
    if (nvox <= 0) return;
    int total = nvox * KOFF;
    for (int p = tid; p < total; p += 256) {
      int voxl = p / KOFF;          // compiler emits magic-mul for /27
      int ko = p - voxl * KOFF;
      int g = tileBase * KOFF + p;
      int idx = __builtin_nontemporal_load(&nidx[g]);
      int mk = bytemode ? (int)__builtin_nontemporal_load(&nmask[g])
                        : __builtin_nontemporal_load(&nmask32[g]);
      lds[voxl * 29 + ko] = (idx & 0x7FFFFFFF) | (mk ? (int)0x80000000 : 0);
    }
    __syncthreads();
    if (tid < nvox) {
#pragma unroll
      for (int ko = 0; ko < KOFF; ++ko) {
        __builtin_nontemporal_store(lds[tid * 29 + ko],
                                    &nbrT[(size_t)ko * N + tileBase + tid]);
      }
    }
  }
}

__launch_bounds__(256)
__global__ void conv_mfma_t(const _Float16* __restrict__ f16,
                            const _Float16* __restrict__ wp,
                            const int* __restrict__ nbrT,
                            float* __restrict__ y,
                            float* __restrict__ stats, int N) {
  __shared__ float smS[4 * 32];
  __shared__ float smQ[4 * 32];
  int wave = threadIdx.x >> 6;
  int lane = threadIdx.x & 63;
  int base = (blockIdx.x * 4 + wave) * 64;
  bool active = base < N;
  int col = lane & 15, quad = lane >> 4;
  const half8* wfrag = (const half8*)wp;

  floatx4 acc[4][2];
#pragma unroll
  for (int t = 0; t < 4; ++t)
#pragma unroll
    for (int h = 0; h < 2; ++h) {
      acc[t][h][0] = 0.f; acc[t][h][1] = 0.f;
      acc[t][h][2] = 0.f; acc[t][h][3] = 0.f;
    }

  if (active) {
    // software pipeline: nbrT for iteration ko+1 prefetched during ko
    int vcur[4];
#pragma unroll
    for (int t = 0; t < 4; ++t)
      vcur[t] = __builtin_nontemporal_load(&nbrT[(size_t)base + t * 16 + col]);

#pragma unroll 3
    for (int ko = 0; ko < KOFF; ++ko) {
      int vnext[4] = {0, 0, 0, 0};
      if (ko + 1 < KOFF) {
#pragma unroll
        for (int t = 0; t < 4; ++t)
          vnext[t] = __builtin_nontemporal_load(
              &nbrT[(size_t)(ko + 1) * N + base + t * 16 + col]);
      }
      half8 b0 = wfrag[(size_t)(ko * 2 + 0) * 64 + lane];
      half8 b1 = wfrag[(size_t)(ko * 2 + 1) * 64 + lane];
#pragma unroll
      for (int t = 0; t < 4; ++t) {
        half8 a;
#pragma unroll
        for (int j = 0; j < 8; ++j) a[j] = (_Float16)0.f;
        if (vcur[t] < 0) {  // bit31 == valid
          int nb = vcur[t] & 0x7FFFFFFF;
          a = *(const half8*)(f16 + (size_t)nb * CIN + quad * 8);
        }
        acc[t][0] = __builtin_amdgcn_mfma_f32_16x16x32_f16(a, b0, acc[t][0], 0, 0, 0);
        acc[t][1] = __builtin_amdgcn_mfma_f32_16x16x32_f16(a, b1, acc[t][1], 0, 0, 0);
      }
#pragma unroll
      for (int t = 0; t < 4; ++t) vcur[t] = vnext[t];
    }
  }

  // ---- epilogue: y store + fused BN partial sums ----
  float s0 = 0.f, s1 = 0.f, q0 = 0.f, q1 = 0.f;
  if (active) {
#pragma unroll
    for (int t = 0; t < 4; ++t) {
#pragma unroll
      for (int h = 0; h < 2; ++h) {
        floatx4 c = acc[t][h];
        int co = h * 16 + col;
#pragma unroll
        for (int r = 0; r < 4; ++r) {
          int vox = base + t * 16 + quad * 4 + r;
          y[(size_t)vox * COUT + co] = c[r];
          float v = c[r];
          if (h == 0) { s0 += v; q0 += v * v; }
          else        { s1 += v; q1 += v * v; }
        }
      }
    }
  }
  // reduce across the 4 quads (lanes col, col+16, col+32, col+48)
  s0 += __shfl_xor(s0, 16); s0 += __shfl_xor(s0, 32);
  s1 += __shfl_xor(s1, 16); s1 += __shfl_xor(s1, 32);
  q0 += __shfl_xor(q0, 16); q0 += __shfl_xor(q0, 32);
  q1 += __shfl_xor(q1, 16); q1 += __shfl_xor(q1, 32);
  if (quad == 0) {
    smS[wave * 32 + col] = s0;
    smS[wave * 32 + 16 + col] = s1;
    smQ[wave * 32 + col] = q0;
    smQ[wave * 32 + 16 + col] = q1;
  }
  __syncthreads();
  int tid = threadIdx.x;
  if (tid < 64) {
    int co = tid & 31;
    const float* arr = (tid < 32) ? smS : smQ;
    float s = arr[co] + arr[32 + co] + arr[64 + co] + arr[96 + co];
    atomicAdd(&stats[(tid < 32 ? 0 : 32) + co], s);
  }
}

// BN finalize (per-block, from raw sums) + normalize + ReLU, in place.
__global__ void bn_apply(float* __restrict__ y, const float* __restrict__ stats,
                         const float* __restrict__ gamma,
                         const float* __restrict__ beta, int total4, float invN) {
  __shared__ float sc_sh[64];
  int tid = threadIdx.x;
  if (tid < 32) {
    float mean = stats[tid] * invN;
    float ex2 = stats[32 + tid] * invN;
    float var = ex2 - mean * mean;
    float inv = rsqrtf(var + EPSV);
    float sc = gamma[tid] * inv;
    sc_sh[tid] = sc;
    sc_sh[32 + tid] = beta[tid] - mean * sc;
  }
  __syncthreads();
  int t = blockIdx.x * blockDim.x + tid;
  if (t >= total4) return;
  size_t g = (size_t)t * 4;
  int co = (int)(g & 31);
  floatx4 v = *(const floatx4*)(y + g);
  floatx4 sc = *(const floatx4*)&sc_sh[co];
  floatx4 sh = *(const floatx4*)&sc_sh[32 + co];
  floatx4 o;
#pragma unroll
  for (int j = 0; j < 4; ++j) o[j] = fmaxf(0.f, v[j] * sc[j] + sh[j]);
  __builtin_nontemporal_store(o, (floatx4*)(y + g));
}

extern "C" void kernel_launch(void* const* d_in, const int* in_sizes, int n_in,
                              void* d_out, int out_size, void* d_ws,
                              size_t ws_size, hipStream_t stream) {
  const float* feats = (const float*)d_in[0];
  const float* W = (const float*)d_in[1];
  const float* gamma = (const float*)d_in[2];
  const float* beta = (const float*)d_in[3];
  const int* nidx = (const int*)d_in[4];
  const unsigned char* nmask = (const unsigned char*)d_in[5];
  float* out = (float*)d_out;

  int N = in_sizes[0] / CIN;  // 1,000,000

  char* ws = (char*)d_ws;
  size_t f16_bytes = (size_t)N * CIN * sizeof(_Float16);
  _Float16* f16 = (_Float16*)ws;
  _Float16* wp = (_Float16*)(ws + f16_bytes);
  size_t wp_bytes = (size_t)KOFF * 2 * 64 * 8 * sizeof(_Float16);
  size_t stats_off = ((f16_bytes + wp_bytes + 511) / 512) * 512;
  float* stats = (float*)(ws + stats_off);
  int* flag = (int*)(stats + 64);
  size_t nbrT_off = ((stats_off + 768 + 255) / 256) * 256;
  int* nbrT = (int*)(ws + nbrT_off);

  hipMemsetAsync(stats, 0, 65 * sizeof(float), stream);

  setup_k<<<KOFF + 1, 128, 0, stream>>>(W, wp, nmask, flag);

  int total8 = N * CIN / 8;
  int cvtBlocks = (total8 + 255) / 256;
  int nbrBlocks = (N + 255) / 256;
  prep_k<<<cvtBlocks + nbrBlocks, 256, 0, stream>>>(feats, f16, total8, nidx,
                                                    nmask, flag, nbrT, N,
                                                    cvtBlocks);

  int nwaves = (N + 63) / 64;
  int nblocks = (nwaves + 3) / 4;
  conv_mfma_t<<<nblocks, 256, 0, stream>>>(f16, wp, nbrT, out, stats, N);

  int total4 = N * COUT / 4;
  bn_apply<<<(total4 + 255) / 256, 256, 0, stream>>>(out, stats, gamma, beta,
                                                     total4, 1.0f / (float)N);
}